// Round 2
// baseline (1479.086 us; speedup 1.0000x reference)
//
#include <hip/hip_runtime.h>
#include <hip/hip_bf16.h>

#define B_ 4
#define E_ 50
#define C_ 64
#define HW_ 2048
#define CHW_ 131072          // C_*HW_ (== NH_*HW_)
#define BE_ 200
#define NH_ 64
#define NM_ 64
#define EE_ 2500             // E_*E_
#define SCALE_ 0.022097086912079608f   // 1/sqrt(2048)

typedef __hip_bfloat16 bf16;

// ---------------- K1a: per-(b,e) partial sums for LayerNorm stats ----------------
__global__ __launch_bounds__(256) void k_stats_p(const float* __restrict__ x, float* __restrict__ sums) {
  int be = blockIdx.x >> 2, part = blockIdx.x & 3;
  const float4* xb = (const float4*)(x + (size_t)be * CHW_) + (size_t)part * 8192;
  float s = 0.f, ss = 0.f;
  #pragma unroll 4
  for (int i = threadIdx.x; i < 8192; i += 256) {
    float4 v = xb[i];
    s  += (v.x + v.y) + (v.z + v.w);
    ss += (v.x*v.x + v.y*v.y) + (v.z*v.z + v.w*v.w);
  }
  __shared__ float s1[256], s2[256];
  s1[threadIdx.x] = s; s2[threadIdx.x] = ss;
  __syncthreads();
  for (int off = 128; off > 0; off >>= 1) {
    if (threadIdx.x < off) { s1[threadIdx.x] += s1[threadIdx.x+off]; s2[threadIdx.x] += s2[threadIdx.x+off]; }
    __syncthreads();
  }
  if (threadIdx.x == 0) {
    atomicAdd(&sums[be*2],   s1[0]);
    atomicAdd(&sums[be*2+1], s2[0]);
  }
}

// ---------------- K1b: finalize mean / rstd ----------------
__global__ __launch_bounds__(256) void k_stats_f(const float* __restrict__ sums, float* __restrict__ stats) {
  int be = threadIdx.x;
  if (be < BE_) {
    float mu  = sums[be*2] * (1.f/CHW_);
    float var = sums[be*2+1] * (1.f/CHW_) - mu*mu;
    stats[be*2]   = mu;
    stats[be*2+1] = rsqrtf(var + 1e-5f);
  }
}

// ---------------- K2: pre-LN + v,k,q 1x1 convs (bf16 out) ----------------
__global__ __launch_bounds__(256) void k_vkq(const float* __restrict__ x,
                                             const float* __restrict__ lng, const float* __restrict__ lnb,
                                             const float* __restrict__ Wv, const float* __restrict__ Wk,
                                             const float* __restrict__ Wq, const float* __restrict__ stats,
                                             bf16* __restrict__ vout, bf16* __restrict__ kout, bf16* __restrict__ qout) {
  int be = blockIdx.x;
  int p  = blockIdx.y * 256 + threadIdx.x;
  float mu = stats[be*2], rstd = stats[be*2+1];
  const float* xb = x + (size_t)be * CHW_ + p;
  float pre[C_];
  #pragma unroll
  for (int c = 0; c < C_; ++c)
    pre[c] = (xb[(size_t)c*HW_] - mu) * rstd * lng[c*HW_ + p] + lnb[c*HW_ + p];
  size_t ob = (size_t)be * CHW_ + p;
  #pragma unroll 2
  for (int o = 0; o < NH_; ++o) {
    float av = 0.f, ak = 0.f, aq = 0.f;
    #pragma unroll
    for (int c = 0; c < C_; ++c) {        // weight reads are wave-uniform -> s_load
      float pc = pre[c];
      av += Wv[o*C_+c] * pc;
      ak += Wk[o*C_+c] * pc;
      aq += Wq[o*C_+c] * pc;
    }
    vout[ob + (size_t)o*HW_] = __float2bfloat16(av);
    kout[ob + (size_t)o*HW_] = __float2bfloat16(ak);
    qout[ob + (size_t)o*HW_] = __float2bfloat16(aq);
  }
}

// ---------------- K3a: gram partials. one block per (b,head); 8 waves write 8 partial bufs ----------------
__global__ __launch_bounds__(512) void k_gram(const bf16* __restrict__ kin, const bf16* __restrict__ qin,
                                              float* __restrict__ gp) {
  int bc = blockIdx.x;                 // b*NH + c
  int b = bc >> 6, c = bc & 63;
  int tid = threadIdx.x;
  int slice = tid >> 6;                // wave id 0..7
  int pt = tid & 63;
  int ig = pt & 7, jg = pt >> 3;       // 8x8 thread grid over padded 64x64 (i,j)
  __shared__ float kl[64][68];         // [hw-row][i], stride 68 floats (272B, 16B aligned)
  __shared__ float ql[64][68];
  float acc[8][8];
  #pragma unroll
  for (int a = 0; a < 8; ++a)
    #pragma unroll
    for (int bb = 0; bb < 8; ++bb) acc[a][bb] = 0.f;
  size_t base = (size_t)b * E_ * CHW_ + (size_t)c * HW_;
  for (int cc = 0; cc < 32; ++cc) {    // 32 chunks of 64 hw rows
    for (int idx = tid; idx < 4096; idx += 512) {
      int i = idx >> 6, row = idx & 63;   // adjacent tid -> adjacent hw: coalesced global
      float kv = 0.f, qv = 0.f;
      if (i < E_) {
        size_t gidx = base + (size_t)i * CHW_ + cc*64 + row;
        kv = __bfloat162float(kin[gidx]);
        qv = __bfloat162float(qin[gidx]);
      }
      kl[row][i] = kv;
      ql[row][i] = qv;
    }
    __syncthreads();
    #pragma unroll
    for (int hh = 0; hh < 8; ++hh) {
      int row = slice*8 + hh;
      float4 k0 = *(const float4*)&kl[row][ig*8];
      float4 k1 = *(const float4*)&kl[row][ig*8+4];
      float4 q0 = *(const float4*)&ql[row][jg*8];
      float4 q1 = *(const float4*)&ql[row][jg*8+4];
      float kv[8] = {k0.x,k0.y,k0.z,k0.w,k1.x,k1.y,k1.z,k1.w};
      float qv[8] = {q0.x,q0.y,q0.z,q0.w,q1.x,q1.y,q1.z,q1.w};
      #pragma unroll
      for (int a = 0; a < 8; ++a)
        #pragma unroll
        for (int bb = 0; bb < 8; ++bb) acc[a][bb] += kv[a]*qv[bb];
    }
    __syncthreads();
  }
  float* gb = gp + ((size_t)slice * (B_*NH_) + bc) * EE_;
  #pragma unroll
  for (int a = 0; a < 8; ++a) {
    int i = ig*8 + a;
    if (i < E_) {
      #pragma unroll
      for (int bb = 0; bb < 8; ++bb) {
        int j = jg*8 + bb;
        if (j < E_) gb[i*E_ + j] = acc[a][bb];
      }
    }
  }
}

// ---------------- K3b: sum partials, scale, softmax over i (per b,c,j) ----------------
__global__ __launch_bounds__(64) void k_softmax(const float* __restrict__ gp, float* __restrict__ wts) {
  int bc = blockIdx.x;
  int j = threadIdx.x;
  if (j >= E_) return;
  float lgt[E_];
  #pragma unroll
  for (int i = 0; i < E_; ++i) {
    float s = 0.f;
    #pragma unroll
    for (int sl = 0; sl < 8; ++sl) s += gp[((size_t)sl*(B_*NH_) + bc)*EE_ + i*E_ + j];
    lgt[i] = s * SCALE_;
  }
  float m = -1e30f;
  #pragma unroll
  for (int i = 0; i < E_; ++i) m = fmaxf(m, lgt[i]);
  float den = 0.f;
  #pragma unroll
  for (int i = 0; i < E_; ++i) { lgt[i] = expf(lgt[i] - m); den += lgt[i]; }
  float inv = 1.f / den;
  float* wb = wts + (size_t)bc * EE_;
  #pragma unroll
  for (int i = 0; i < E_; ++i) wb[i*E_ + j] = lgt[i] * inv;   // [i][j] layout, coalesced across j
}

// ---------------- K4: ensemble mixing. transformed_j = v_j - vmean + sum_i w[i,j] v_i ----------------
// (uses sum_i w[i,j] == 1 from softmax)
__global__ __launch_bounds__(256) void k_mix(const bf16* __restrict__ vin, const float* __restrict__ wts,
                                             bf16* __restrict__ tout) {
  int bc = blockIdx.x;                 // b*NH + c
  int b = bc >> 6, c = bc & 63;
  int p = blockIdx.y * 256 + threadIdx.x;
  size_t base = (size_t)b * E_ * CHW_ + (size_t)c * HW_ + p;
  const float* wb = wts + (size_t)bc * EE_;
  float acc[E_];
  #pragma unroll
  for (int j = 0; j < E_; ++j) acc[j] = 0.f;
  float vsum = 0.f;
  #pragma unroll 2
  for (int i = 0; i < E_; ++i) {       // stream v_i; w reads wave-uniform, consecutive in j -> s_load_dwordx
    float vi = __bfloat162float(vin[base + (size_t)i * CHW_]);
    vsum += vi;
    #pragma unroll
    for (int j = 0; j < E_; ++j) acc[j] += wb[i*E_+j] * vi;
  }
  float vmean = vsum * (1.f/E_);
  #pragma unroll
  for (int j = 0; j < E_; ++j) {
    float vj = __bfloat162float(vin[base + (size_t)j * CHW_]);
    tout[base + (size_t)j * CHW_] = __float2bfloat16(vj - vmean + acc[j]);
  }
}

// ---------------- K5: after = x + Wout*t ; out = after + MLP(after) (fused, no h1 array) ----------------
__global__ __launch_bounds__(256) void k_final(const bf16* __restrict__ tin, const float* __restrict__ x,
                                               const float* __restrict__ Wo, const float* __restrict__ Wm1,
                                               const float* __restrict__ bm1, const float* __restrict__ Wm2,
                                               const float* __restrict__ bm2, float* __restrict__ out) {
  int be = blockIdx.x;
  int p = blockIdx.y * 256 + threadIdx.x;
  size_t base = (size_t)be * CHW_ + p;
  float after[C_];
  #pragma unroll
  for (int c = 0; c < C_; ++c) after[c] = 0.f;
  #pragma unroll 2
  for (int o = 0; o < NH_; ++o) {      // stream t_o
    float to = __bfloat162float(tin[base + (size_t)o * HW_]);
    #pragma unroll
    for (int c = 0; c < C_; ++c) after[c] += Wo[c*NH_+o] * to;
  }
  #pragma unroll
  for (int c = 0; c < C_; ++c) after[c] += x[base + (size_t)c * HW_];
  float acc[C_];
  #pragma unroll
  for (int c = 0; c < C_; ++c) acc[c] = 0.f;
  #pragma unroll 2
  for (int m = 0; m < NM_; ++m) {      // hidden unit m: produce, gelu, consume immediately
    float a = bm1[m];
    #pragma unroll
    for (int c = 0; c < C_; ++c) a += Wm1[m*C_+c] * after[c];
    float g = 0.5f * a * (1.f + erff(a * 0.70710678118654752440f));
    #pragma unroll
    for (int c = 0; c < C_; ++c) acc[c] += Wm2[c*NM_+m] * g;
  }
  #pragma unroll
  for (int c = 0; c < C_; ++c)
    out[base + (size_t)c * HW_] = after[c] + acc[c] + bm2[c];
}

extern "C" void kernel_launch(void* const* d_in, const int* in_sizes, int n_in,
                              void* d_out, int out_size, void* d_ws, size_t ws_size,
                              hipStream_t stream) {
  (void)in_sizes; (void)n_in; (void)out_size; (void)ws_size;
  const float* x   = (const float*)d_in[0];
  const float* lng = (const float*)d_in[1];
  const float* lnb = (const float*)d_in[2];
  const float* Wv  = (const float*)d_in[3];
  const float* Wk  = (const float*)d_in[4];
  const float* Wq  = (const float*)d_in[5];
  const float* Wo  = (const float*)d_in[6];
  const float* Wm1 = (const float*)d_in[7];
  const float* bm1 = (const float*)d_in[8];
  const float* Wm2 = (const float*)d_in[9];
  const float* bm2 = (const float*)d_in[10];
  float* out = (float*)d_out;

  char* ws = (char*)d_ws;
  size_t off = 0;
  float* sums  = (float*)(ws + off); off += 2048;                       // 200*2 f32 (zeroed)
  float* stats = (float*)(ws + off); off += 2048;                       // 200*2 f32
  float* wts   = (float*)(ws + off); off += (size_t)B_*NH_*EE_*4;       // 2.56 MB
  float* gramp = (float*)(ws + off); off += (size_t)8*B_*NH_*EE_*4;     // 20.48 MB (8 wave-partials)
  bf16* vbuf   = (bf16*)(ws + off);  off += (size_t)BE_*CHW_*2;         // 52.4 MB
  bf16* kbuf   = (bf16*)(ws + off);  off += (size_t)BE_*CHW_*2;
  bf16* qbuf   = (bf16*)(ws + off);  off += (size_t)BE_*CHW_*2;
  bf16* tbuf   = kbuf;  // k is dead after k_gram; reuse for transformed

  hipMemsetAsync(sums, 0, 2048, stream);
  k_stats_p<<<dim3(BE_*4), 256, 0, stream>>>(x, sums);
  k_stats_f<<<dim3(1), 256, 0, stream>>>(sums, stats);
  k_vkq<<<dim3(BE_, 8), 256, 0, stream>>>(x, lng, lnb, Wv, Wk, Wq, stats, vbuf, kbuf, qbuf);
  k_gram<<<dim3(B_*NH_), 512, 0, stream>>>(kbuf, qbuf, gramp);
  k_softmax<<<dim3(B_*NH_), 64, 0, stream>>>(gramp, wts);
  k_mix<<<dim3(B_*NH_, 8), 256, 0, stream>>>(vbuf, wts, tbuf);
  k_final<<<dim3(BE_, 8), 256, 0, stream>>>(tbuf, x, Wo, Wm1, bm1, Wm2, bm2, out);
}

// Round 3
// 562.376 us; speedup vs baseline: 2.6301x; 2.6301x over previous
//
#include <hip/hip_runtime.h>
#include <hip/hip_bf16.h>

#define B_ 4
#define E_ 50
#define C_ 64
#define HW_ 2048
#define CHW_ 131072          // C_*HW_ (== NH_*HW_)
#define BE_ 200
#define NH_ 64
#define NM_ 64
#define EE_ 2500             // E_*E_
#define SCALE_ 0.022097086912079608f   // 1/sqrt(2048)

#define PSTR 134             // bf16 elems per activation LDS row (268B): conflict-free u16 col reads
#define WSTR 72              // bf16 elems per weight LDS row (144B): 16B-aligned b128 rows

typedef __hip_bfloat16 bf16;
typedef __attribute__((ext_vector_type(8))) short bf16x8;   // 8 bf16 = 4 VGPR (MFMA A/B frag)
typedef __attribute__((ext_vector_type(4))) float f32x4;    // MFMA C/D frag

__device__ __forceinline__ short f2b(float f) {
  __hip_bfloat16 h = __float2bfloat16(f);
  return *reinterpret_cast<short*>(&h);
}
__device__ __forceinline__ unsigned pack2(float a, float b) {
  return (unsigned)(unsigned short)f2b(a) | ((unsigned)(unsigned short)f2b(b) << 16);
}

// ---------------- K1a: per-(b,e) partial sums for LayerNorm stats ----------------
__global__ __launch_bounds__(256) void k_stats_p(const float* __restrict__ x, float* __restrict__ sums) {
  int be = blockIdx.x >> 2, part = blockIdx.x & 3;
  const float4* xb = (const float4*)(x + (size_t)be * CHW_) + (size_t)part * 8192;
  float s = 0.f, ss = 0.f;
  #pragma unroll 4
  for (int i = threadIdx.x; i < 8192; i += 256) {
    float4 v = xb[i];
    s  += (v.x + v.y) + (v.z + v.w);
    ss += (v.x*v.x + v.y*v.y) + (v.z*v.z + v.w*v.w);
  }
  __shared__ float s1[256], s2[256];
  s1[threadIdx.x] = s; s2[threadIdx.x] = ss;
  __syncthreads();
  for (int off = 128; off > 0; off >>= 1) {
    if (threadIdx.x < off) { s1[threadIdx.x] += s1[threadIdx.x+off]; s2[threadIdx.x] += s2[threadIdx.x+off]; }
    __syncthreads();
  }
  if (threadIdx.x == 0) {
    atomicAdd(&sums[be*2],   s1[0]);
    atomicAdd(&sums[be*2+1], s2[0]);
  }
}

// ---------------- K1b: finalize mean / rstd ----------------
__global__ __launch_bounds__(256) void k_stats_f(const float* __restrict__ sums, float* __restrict__ stats) {
  int be = threadIdx.x;
  if (be < BE_) {
    float mu  = sums[be*2] * (1.f/CHW_);
    float var = sums[be*2+1] * (1.f/CHW_) - mu*mu;
    stats[be*2]   = mu;
    stats[be*2+1] = rsqrtf(var + 1e-5f);
  }
}

// ---------------- K2: pre-LN + v,k,q 1x1 convs via MFMA ----------------
// GEMM per block: D[n=192][p=128] = W[192][64] * pre[64][p=128]
// A = W from LDS [n][k] (b128 reads), B = pre from LDS [k][p] (8x ds_read_u16)
// D: col=lane&15 = p, row=(lane>>4)*4+reg = n   [m89-verified]
__global__ __launch_bounds__(256) void k_vkq(const float* __restrict__ x,
                                             const float* __restrict__ lng, const float* __restrict__ lnb,
                                             const float* __restrict__ Wv, const float* __restrict__ Wk,
                                             const float* __restrict__ Wq, const float* __restrict__ stats,
                                             bf16* __restrict__ vout, bf16* __restrict__ kout, bf16* __restrict__ qout) {
  __shared__ short wl[192*WSTR];    // 27.6 KB: [Wv;Wk;Wq] rows as [n][c]
  __shared__ short prel[64*PSTR];   // 17.2 KB: pre tile [c][p]
  int be = blockIdx.x, p0 = blockIdx.y * 128;
  int tid = threadIdx.x;
  // stage weights f32->bf16 (6144 packed pairs)
  for (int idx = tid; idx < 6144; idx += 256) {
    int n = idx >> 5, cp = idx & 31;
    const float* Wsrc = (n < 64) ? Wv : (n < 128 ? Wk : Wq);
    float2 wv = *(const float2*)&Wsrc[(n & 63)*64 + cp*2];
    *(unsigned*)&wl[n*WSTR + cp*2] = pack2(wv.x, wv.y);
  }
  // stage pre = LN(x): thread covers (c=crow+8k, p=p0+4j..+3)
  float mu = stats[be*2], rstd = stats[be*2+1];
  int j = tid & 31, crow = tid >> 5;
  int p = p0 + j*4;
  #pragma unroll
  for (int c = crow; c < 64; c += 8) {
    size_t gi = (size_t)c*HW_ + p;
    float4 xv = *(const float4*)&x[(size_t)be*CHW_ + gi];
    float4 gv = *(const float4*)&lng[gi];
    float4 bv = *(const float4*)&lnb[gi];
    float r0 = (xv.x-mu)*rstd*gv.x + bv.x;
    float r1 = (xv.y-mu)*rstd*gv.y + bv.y;
    float r2 = (xv.z-mu)*rstd*gv.z + bv.z;
    float r3 = (xv.w-mu)*rstd*gv.w + bv.w;
    *(unsigned*)&prel[c*PSTR + j*4]     = pack2(r0, r1);
    *(unsigned*)&prel[c*PSTR + j*4 + 2] = pack2(r2, r3);
  }
  __syncthreads();
  int wave = tid >> 6, lane = tid & 63, lg = lane >> 4, l16 = lane & 15;
  const f32x4 vzero = {0.f, 0.f, 0.f, 0.f};
  f32x4 acc[12][2];
  #pragma unroll
  for (int mf = 0; mf < 12; ++mf) { acc[mf][0] = vzero; acc[mf][1] = vzero; }
  #pragma unroll
  for (int cf = 0; cf < 2; ++cf) {
    int colb = (wave*2 + cf)*16;
    #pragma unroll
    for (int kf = 0; kf < 2; ++kf) {
      bf16x8 bfr;
      #pragma unroll
      for (int e = 0; e < 8; ++e)
        bfr[e] = prel[(kf*32 + lg*8 + e)*PSTR + colb + l16];
      #pragma unroll
      for (int mf = 0; mf < 12; ++mf) {
        bf16x8 afr = *(const bf16x8*)&wl[(mf*16 + l16)*WSTR + kf*32 + lg*8];
        acc[mf][cf] = __builtin_amdgcn_mfma_f32_16x16x32_bf16(afr, bfr, acc[mf][cf], 0, 0, 0);
      }
    }
  }
  // store: n = mf*16 + lg*4 + r, p = p0 + (wave*2+cf)*16 + l16
  #pragma unroll
  for (int mf = 0; mf < 12; ++mf) {
    bf16* dst = (mf < 4) ? vout : (mf < 8 ? kout : qout);
    int nn = (mf & 3)*16 + lg*4;
    #pragma unroll
    for (int cf = 0; cf < 2; ++cf) {
      int pp = p0 + (wave*2 + cf)*16 + l16;
      size_t basep = (size_t)be*CHW_ + pp;
      #pragma unroll
      for (int r = 0; r < 4; ++r)
        dst[basep + (size_t)(nn + r)*HW_] = __float2bfloat16(acc[mf][cf][r]);
    }
  }
}

// ---------------- K3a: gram partials (unchanged) ----------------
__global__ __launch_bounds__(512) void k_gram(const bf16* __restrict__ kin, const bf16* __restrict__ qin,
                                              float* __restrict__ gp) {
  int bc = blockIdx.x;
  int b = bc >> 6, c = bc & 63;
  int tid = threadIdx.x;
  int slice = tid >> 6;
  int pt = tid & 63;
  int ig = pt & 7, jg = pt >> 3;
  __shared__ float kl[64][68];
  __shared__ float ql[64][68];
  float acc[8][8];
  #pragma unroll
  for (int a = 0; a < 8; ++a)
    #pragma unroll
    for (int bb = 0; bb < 8; ++bb) acc[a][bb] = 0.f;
  size_t base = (size_t)b * E_ * CHW_ + (size_t)c * HW_;
  for (int cc = 0; cc < 32; ++cc) {
    for (int idx = tid; idx < 4096; idx += 512) {
      int i = idx >> 6, row = idx & 63;
      float kv = 0.f, qv = 0.f;
      if (i < E_) {
        size_t gidx = base + (size_t)i * CHW_ + cc*64 + row;
        kv = __bfloat162float(kin[gidx]);
        qv = __bfloat162float(qin[gidx]);
      }
      kl[row][i] = kv;
      ql[row][i] = qv;
    }
    __syncthreads();
    #pragma unroll
    for (int hh = 0; hh < 8; ++hh) {
      int row = slice*8 + hh;
      float4 k0 = *(const float4*)&kl[row][ig*8];
      float4 k1 = *(const float4*)&kl[row][ig*8+4];
      float4 q0 = *(const float4*)&ql[row][jg*8];
      float4 q1 = *(const float4*)&ql[row][jg*8+4];
      float kv[8] = {k0.x,k0.y,k0.z,k0.w,k1.x,k1.y,k1.z,k1.w};
      float qv[8] = {q0.x,q0.y,q0.z,q0.w,q1.x,q1.y,q1.z,q1.w};
      #pragma unroll
      for (int a = 0; a < 8; ++a)
        #pragma unroll
        for (int bb = 0; bb < 8; ++bb) acc[a][bb] += kv[a]*qv[bb];
    }
    __syncthreads();
  }
  float* gb = gp + ((size_t)slice * (B_*NH_) + bc) * EE_;
  #pragma unroll
  for (int a = 0; a < 8; ++a) {
    int i = ig*8 + a;
    if (i < E_) {
      #pragma unroll
      for (int bb = 0; bb < 8; ++bb) {
        int j = jg*8 + bb;
        if (j < E_) gb[i*E_ + j] = acc[a][bb];
      }
    }
  }
}

// ---------------- K3b: softmax (unchanged) ----------------
__global__ __launch_bounds__(64) void k_softmax(const float* __restrict__ gp, float* __restrict__ wts) {
  int bc = blockIdx.x;
  int j = threadIdx.x;
  if (j >= E_) return;
  float lgt[E_];
  #pragma unroll
  for (int i = 0; i < E_; ++i) {
    float s = 0.f;
    #pragma unroll
    for (int sl = 0; sl < 8; ++sl) s += gp[((size_t)sl*(B_*NH_) + bc)*EE_ + i*E_ + j];
    lgt[i] = s * SCALE_;
  }
  float m = -1e30f;
  #pragma unroll
  for (int i = 0; i < E_; ++i) m = fmaxf(m, lgt[i]);
  float den = 0.f;
  #pragma unroll
  for (int i = 0; i < E_; ++i) { lgt[i] = expf(lgt[i] - m); den += lgt[i]; }
  float inv = 1.f / den;
  float* wb = wts + (size_t)bc * EE_;
  #pragma unroll
  for (int i = 0; i < E_; ++i) wb[i*E_ + j] = lgt[i] * inv;
}

// ---------------- K4: ensemble mixing (unchanged) ----------------
__global__ __launch_bounds__(256) void k_mix(const bf16* __restrict__ vin, const float* __restrict__ wts,
                                             bf16* __restrict__ tout) {
  int bc = blockIdx.x;
  int b = bc >> 6, c = bc & 63;
  int p = blockIdx.y * 256 + threadIdx.x;
  size_t base = (size_t)b * E_ * CHW_ + (size_t)c * HW_ + p;
  const float* wb = wts + (size_t)bc * EE_;
  float acc[E_];
  #pragma unroll
  for (int j = 0; j < E_; ++j) acc[j] = 0.f;
  float vsum = 0.f;
  #pragma unroll 2
  for (int i = 0; i < E_; ++i) {
    float vi = __bfloat162float(vin[base + (size_t)i * CHW_]);
    vsum += vi;
    #pragma unroll
    for (int j = 0; j < E_; ++j) acc[j] += wb[i*E_+j] * vi;
  }
  float vmean = vsum * (1.f/E_);
  #pragma unroll
  for (int j = 0; j < E_; ++j) {
    float vj = __bfloat162float(vin[base + (size_t)j * CHW_]);
    tout[base + (size_t)j * CHW_] = __float2bfloat16(vj - vmean + acc[j]);
  }
}

// ---------------- K5: after = x + Wo*t ; out = after + MLP(after) via 3 chained MFMA GEMMs ----------------
__global__ __launch_bounds__(256) void k_final(const bf16* __restrict__ tin, const float* __restrict__ x,
                                               const float* __restrict__ Wo, const float* __restrict__ Wm1,
                                               const float* __restrict__ bm1, const float* __restrict__ Wm2,
                                               const float* __restrict__ bm2, float* __restrict__ out) {
  __shared__ short wl[192*WSTR];   // Wo | Wm1 | Wm2, each [64][64] as [n][k]
  __shared__ short tl[64*PSTR];    // t tile [o][p]
  __shared__ short al[64*PSTR];    // after / gelu bounce [k][p]
  int be = blockIdx.x, p0 = blockIdx.y * 128;
  int tid = threadIdx.x;
  for (int idx = tid; idx < 6144; idx += 256) {
    int n = idx >> 5, cp = idx & 31;
    const float* Wsrc = (n < 64) ? Wo : (n < 128 ? Wm1 : Wm2);
    float2 wv = *(const float2*)&Wsrc[(n & 63)*64 + cp*2];
    *(unsigned*)&wl[n*WSTR + cp*2] = pack2(wv.x, wv.y);
  }
  for (int idx = tid; idx < 4096; idx += 256) {   // t already bf16: copy 4B chunks
    int o = idx >> 6, seg = idx & 63;
    *(unsigned*)&tl[o*PSTR + seg*2] =
        *(const unsigned*)&tin[(size_t)be*CHW_ + (size_t)o*HW_ + p0 + seg*2];
  }
  __syncthreads();
  int wave = tid >> 6, lane = tid & 63, lg = lane >> 4, l16 = lane & 15;
  int colb0 = wave*32;
  const f32x4 vzero = {0.f, 0.f, 0.f, 0.f};

  // GEMM1: after = Wo * t
  f32x4 aft[4][2];
  #pragma unroll
  for (int mf = 0; mf < 4; ++mf) { aft[mf][0] = vzero; aft[mf][1] = vzero; }
  #pragma unroll
  for (int cf = 0; cf < 2; ++cf) {
    int colb = colb0 + cf*16;
    #pragma unroll
    for (int kf = 0; kf < 2; ++kf) {
      bf16x8 bfr;
      #pragma unroll
      for (int e = 0; e < 8; ++e) bfr[e] = tl[(kf*32 + lg*8 + e)*PSTR + colb + l16];
      #pragma unroll
      for (int mf = 0; mf < 4; ++mf) {
        bf16x8 afr = *(const bf16x8*)&wl[(mf*16 + l16)*WSTR + kf*32 + lg*8];
        aft[mf][cf] = __builtin_amdgcn_mfma_f32_16x16x32_bf16(afr, bfr, aft[mf][cf], 0, 0, 0);
      }
    }
  }
  // + x residual (keep f32 in regs), bounce bf16 copy into al
  #pragma unroll
  for (int mf = 0; mf < 4; ++mf) {
    int c0 = mf*16 + lg*4;
    #pragma unroll
    for (int cf = 0; cf < 2; ++cf) {
      int pp = p0 + colb0 + cf*16 + l16;
      #pragma unroll
      for (int r = 0; r < 4; ++r) {
        float v = aft[mf][cf][r] + x[(size_t)be*CHW_ + (size_t)(c0+r)*HW_ + pp];
        aft[mf][cf][r] = v;
        al[(c0+r)*PSTR + colb0 + cf*16 + l16] = f2b(v);
      }
    }
  }
  __syncthreads();
  // GEMM2: h1 = Wm1 * after + bm1 -> gelu
  f32x4 hh[4][2];
  #pragma unroll
  for (int mf = 0; mf < 4; ++mf) { hh[mf][0] = vzero; hh[mf][1] = vzero; }
  #pragma unroll
  for (int cf = 0; cf < 2; ++cf) {
    int colb = colb0 + cf*16;
    #pragma unroll
    for (int kf = 0; kf < 2; ++kf) {
      bf16x8 bfr;
      #pragma unroll
      for (int e = 0; e < 8; ++e) bfr[e] = al[(kf*32 + lg*8 + e)*PSTR + colb + l16];
      #pragma unroll
      for (int mf = 0; mf < 4; ++mf) {
        bf16x8 afr = *(const bf16x8*)&wl[((64 + mf*16 + l16))*WSTR + kf*32 + lg*8];
        hh[mf][cf] = __builtin_amdgcn_mfma_f32_16x16x32_bf16(afr, bfr, hh[mf][cf], 0, 0, 0);
      }
    }
  }
  __syncthreads();   // all reads of al done before overwrite
  #pragma unroll
  for (int mf = 0; mf < 4; ++mf) {
    int m0 = mf*16 + lg*4;
    #pragma unroll
    for (int cf = 0; cf < 2; ++cf) {
      #pragma unroll
      for (int r = 0; r < 4; ++r) {
        float hv = hh[mf][cf][r] + bm1[m0 + r];
        float g = 0.5f * hv * (1.f + erff(hv * 0.70710678118654752440f));
        al[(m0+r)*PSTR + colb0 + cf*16 + l16] = f2b(g);
      }
    }
  }
  __syncthreads();
  // GEMM3: mix = Wm2 * gelu ; out = after + mix + bm2
  f32x4 mx[4][2];
  #pragma unroll
  for (int mf = 0; mf < 4; ++mf) { mx[mf][0] = vzero; mx[mf][1] = vzero; }
  #pragma unroll
  for (int cf = 0; cf < 2; ++cf) {
    int colb = colb0 + cf*16;
    #pragma unroll
    for (int kf = 0; kf < 2; ++kf) {
      bf16x8 bfr;
      #pragma unroll
      for (int e = 0; e < 8; ++e) bfr[e] = al[(kf*32 + lg*8 + e)*PSTR + colb + l16];
      #pragma unroll
      for (int mf = 0; mf < 4; ++mf) {
        bf16x8 afr = *(const bf16x8*)&wl[((128 + mf*16 + l16))*WSTR + kf*32 + lg*8];
        mx[mf][cf] = __builtin_amdgcn_mfma_f32_16x16x32_bf16(afr, bfr, mx[mf][cf], 0, 0, 0);
      }
    }
  }
  #pragma unroll
  for (int mf = 0; mf < 4; ++mf) {
    int c0 = mf*16 + lg*4;
    #pragma unroll
    for (int cf = 0; cf < 2; ++cf) {
      int pp = p0 + colb0 + cf*16 + l16;
      #pragma unroll
      for (int r = 0; r < 4; ++r)
        out[(size_t)be*CHW_ + (size_t)(c0+r)*HW_ + pp] = aft[mf][cf][r] + mx[mf][cf][r] + bm2[c0+r];
    }
  }
}

extern "C" void kernel_launch(void* const* d_in, const int* in_sizes, int n_in,
                              void* d_out, int out_size, void* d_ws, size_t ws_size,
                              hipStream_t stream) {
  (void)in_sizes; (void)n_in; (void)out_size; (void)ws_size;
  const float* x   = (const float*)d_in[0];
  const float* lng = (const float*)d_in[1];
  const float* lnb = (const float*)d_in[2];
  const float* Wv  = (const float*)d_in[3];
  const float* Wk  = (const float*)d_in[4];
  const float* Wq  = (const float*)d_in[5];
  const float* Wo  = (const float*)d_in[6];
  const float* Wm1 = (const float*)d_in[7];
  const float* bm1 = (const float*)d_in[8];
  const float* Wm2 = (const float*)d_in[9];
  const float* bm2 = (const float*)d_in[10];
  float* out = (float*)d_out;

  char* ws = (char*)d_ws;
  size_t off = 0;
  float* sums  = (float*)(ws + off); off += 2048;
  float* stats = (float*)(ws + off); off += 2048;
  float* wts   = (float*)(ws + off); off += (size_t)B_*NH_*EE_*4;
  float* gramp = (float*)(ws + off); off += (size_t)8*B_*NH_*EE_*4;
  bf16* vbuf   = (bf16*)(ws + off);  off += (size_t)BE_*CHW_*2;
  bf16* kbuf   = (bf16*)(ws + off);  off += (size_t)BE_*CHW_*2;
  bf16* qbuf   = (bf16*)(ws + off);  off += (size_t)BE_*CHW_*2;
  bf16* tbuf   = kbuf;  // k dead after k_gram; reuse for transformed

  hipMemsetAsync(sums, 0, 2048, stream);
  k_stats_p<<<dim3(BE_*4), 256, 0, stream>>>(x, sums);
  k_stats_f<<<dim3(1), 256, 0, stream>>>(sums, stats);
  k_vkq<<<dim3(BE_, 16), 256, 0, stream>>>(x, lng, lnb, Wv, Wk, Wq, stats, vbuf, kbuf, qbuf);
  k_gram<<<dim3(B_*NH_), 512, 0, stream>>>(kbuf, qbuf, gramp);
  k_softmax<<<dim3(B_*NH_), 64, 0, stream>>>(gramp, wts);
  k_mix<<<dim3(B_*NH_, 8), 256, 0, stream>>>(vbuf, wts, tbuf);
  k_final<<<dim3(BE_, 16), 256, 0, stream>>>(tbuf, x, Wo, Wm1, bm1, Wm2, bm2, out);
}

// Round 4
// 427.092 us; speedup vs baseline: 3.4632x; 1.3168x over previous
//
#include <hip/hip_runtime.h>
#include <hip/hip_bf16.h>

#define B_ 4
#define E_ 50
#define C_ 64
#define HW_ 2048
#define CHW_ 131072          // C_*HW_ (== NH_*HW_)
#define BE_ 200
#define NH_ 64
#define NM_ 64
#define EE_ 2500             // E_*E_
#define SCALE_ 0.022097086912079608f   // 1/sqrt(2048)

#define PSTR 134             // bf16 elems per activation LDS row (268B): conflict-free u16 col reads
#define WSTR 72              // bf16 elems per weight LDS row (144B): 16B-aligned b128 rows
#define VSTR 132             // k_mix V-tile row stride (264B): 8B-aligned, 2-way max on u16 gather

typedef __hip_bfloat16 bf16;
typedef __attribute__((ext_vector_type(8))) short bf16x8;   // 8 bf16 = 4 VGPR (MFMA A/B frag)
typedef __attribute__((ext_vector_type(4))) float f32x4;    // MFMA C/D frag

__device__ __forceinline__ short f2b(float f) {
  __hip_bfloat16 h = __float2bfloat16(f);
  return *reinterpret_cast<short*>(&h);
}
__device__ __forceinline__ unsigned pack2(float a, float b) {
  return (unsigned)(unsigned short)f2b(a) | ((unsigned)(unsigned short)f2b(b) << 16);
}

// ---------------- K1a: per-(b,e) partial sums for LayerNorm stats ----------------
__global__ __launch_bounds__(256) void k_stats_p(const float* __restrict__ x, float* __restrict__ sums) {
  int be = blockIdx.x >> 2, part = blockIdx.x & 3;
  const float4* xb = (const float4*)(x + (size_t)be * CHW_) + (size_t)part * 8192;
  float s = 0.f, ss = 0.f;
  #pragma unroll 4
  for (int i = threadIdx.x; i < 8192; i += 256) {
    float4 v = xb[i];
    s  += (v.x + v.y) + (v.z + v.w);
    ss += (v.x*v.x + v.y*v.y) + (v.z*v.z + v.w*v.w);
  }
  __shared__ float s1[256], s2[256];
  s1[threadIdx.x] = s; s2[threadIdx.x] = ss;
  __syncthreads();
  for (int off = 128; off > 0; off >>= 1) {
    if (threadIdx.x < off) { s1[threadIdx.x] += s1[threadIdx.x+off]; s2[threadIdx.x] += s2[threadIdx.x+off]; }
    __syncthreads();
  }
  if (threadIdx.x == 0) {
    atomicAdd(&sums[be*2],   s1[0]);
    atomicAdd(&sums[be*2+1], s2[0]);
  }
}

// ---------------- K1b: finalize mean / rstd ----------------
__global__ __launch_bounds__(256) void k_stats_f(const float* __restrict__ sums, float* __restrict__ stats) {
  int be = threadIdx.x;
  if (be < BE_) {
    float mu  = sums[be*2] * (1.f/CHW_);
    float var = sums[be*2+1] * (1.f/CHW_) - mu*mu;
    stats[be*2]   = mu;
    stats[be*2+1] = rsqrtf(var + 1e-5f);
  }
}

// ---------------- K2: pre-LN + v,k,q 1x1 convs via MFMA ----------------
__global__ __launch_bounds__(256) void k_vkq(const float* __restrict__ x,
                                             const float* __restrict__ lng, const float* __restrict__ lnb,
                                             const float* __restrict__ Wv, const float* __restrict__ Wk,
                                             const float* __restrict__ Wq, const float* __restrict__ stats,
                                             bf16* __restrict__ vout, bf16* __restrict__ kout, bf16* __restrict__ qout) {
  __shared__ short wl[192*WSTR];    // 27.6 KB: [Wv;Wk;Wq] rows as [n][c]
  __shared__ short prel[64*PSTR];   // 17.2 KB: pre tile [c][p]
  int be = blockIdx.x, p0 = blockIdx.y * 128;
  int tid = threadIdx.x;
  for (int idx = tid; idx < 6144; idx += 256) {
    int n = idx >> 5, cp = idx & 31;
    const float* Wsrc = (n < 64) ? Wv : (n < 128 ? Wk : Wq);
    float2 wv = *(const float2*)&Wsrc[(n & 63)*64 + cp*2];
    *(unsigned*)&wl[n*WSTR + cp*2] = pack2(wv.x, wv.y);
  }
  float mu = stats[be*2], rstd = stats[be*2+1];
  int j = tid & 31, crow = tid >> 5;
  int p = p0 + j*4;
  #pragma unroll
  for (int c = crow; c < 64; c += 8) {
    size_t gi = (size_t)c*HW_ + p;
    float4 xv = *(const float4*)&x[(size_t)be*CHW_ + gi];
    float4 gv = *(const float4*)&lng[gi];
    float4 bv = *(const float4*)&lnb[gi];
    float r0 = (xv.x-mu)*rstd*gv.x + bv.x;
    float r1 = (xv.y-mu)*rstd*gv.y + bv.y;
    float r2 = (xv.z-mu)*rstd*gv.z + bv.z;
    float r3 = (xv.w-mu)*rstd*gv.w + bv.w;
    *(unsigned*)&prel[c*PSTR + j*4]     = pack2(r0, r1);
    *(unsigned*)&prel[c*PSTR + j*4 + 2] = pack2(r2, r3);
  }
  __syncthreads();
  int wave = tid >> 6, lane = tid & 63, lg = lane >> 4, l16 = lane & 15;
  const f32x4 vzero = {0.f, 0.f, 0.f, 0.f};
  f32x4 acc[12][2];
  #pragma unroll
  for (int mf = 0; mf < 12; ++mf) { acc[mf][0] = vzero; acc[mf][1] = vzero; }
  #pragma unroll
  for (int cf = 0; cf < 2; ++cf) {
    int colb = (wave*2 + cf)*16;
    #pragma unroll
    for (int kf = 0; kf < 2; ++kf) {
      bf16x8 bfr;
      #pragma unroll
      for (int e = 0; e < 8; ++e)
        bfr[e] = prel[(kf*32 + lg*8 + e)*PSTR + colb + l16];
      #pragma unroll
      for (int mf = 0; mf < 12; ++mf) {
        bf16x8 afr = *(const bf16x8*)&wl[(mf*16 + l16)*WSTR + kf*32 + lg*8];
        acc[mf][cf] = __builtin_amdgcn_mfma_f32_16x16x32_bf16(afr, bfr, acc[mf][cf], 0, 0, 0);
      }
    }
  }
  #pragma unroll
  for (int mf = 0; mf < 12; ++mf) {
    bf16* dst = (mf < 4) ? vout : (mf < 8 ? kout : qout);
    int nn = (mf & 3)*16 + lg*4;
    #pragma unroll
    for (int cf = 0; cf < 2; ++cf) {
      int pp = p0 + (wave*2 + cf)*16 + l16;
      size_t basep = (size_t)be*CHW_ + pp;
      #pragma unroll
      for (int r = 0; r < 4; ++r)
        dst[basep + (size_t)(nn + r)*HW_] = __float2bfloat16(acc[mf][cf][r]);
    }
  }
}

// ---------------- K3a: gram via MFMA ----------------
// Per (bc, slice): D[i=64][j=64] += K_tile * Q_tile^T over 512 hw.
// A[i][hw] and B[hw][j]=Q[j][hw] are BOTH b128 row reads from [ens][hw] tiles (XOR-swizzled).
// Pad rows 50..63 left stale: MFMA row/col independence -> only unwritten D rows/cols affected.
__global__ __launch_bounds__(256) void k_gram(const bf16* __restrict__ kin, const bf16* __restrict__ qin,
                                              float* __restrict__ gp) {
  __shared__ short kt[64*128];   // 16 KB, row = 256B = 16 chunks of 16B, chunk ^= (row&15)
  __shared__ short qt[64*128];
  int bc = blockIdx.x, slice = blockIdx.y;
  int b = bc >> 6, c = bc & 63;
  int tid = threadIdx.x;
  int w = tid >> 6, lane = tid & 63, lg = lane >> 4, l16 = lane & 15;
  int wm = w >> 1, wn = w & 1;   // wave quadrant: rows wm*32.., cols wn*32..
  size_t base = (size_t)b * E_ * CHW_ + (size_t)c * HW_;
  const f32x4 vzero = {0.f, 0.f, 0.f, 0.f};
  f32x4 acc[2][2];
  acc[0][0] = vzero; acc[0][1] = vzero; acc[1][0] = vzero; acc[1][1] = vzero;
  for (int s = 0; s < 4; ++s) {
    int hw0 = slice*512 + s*128;
    for (int idx = tid; idx < 800; idx += 256) {     // 50 rows x 16 chunks
      int row = idx >> 4, seg = idx & 15;
      size_t g = base + (size_t)row*CHW_ + hw0 + seg*8;
      uint4 kv = *(const uint4*)&kin[g];
      uint4 qv = *(const uint4*)&qin[g];
      int pos = row*128 + ((seg ^ (row & 15))*8);
      *(uint4*)&kt[pos] = kv;
      *(uint4*)&qt[pos] = qv;
    }
    __syncthreads();
    #pragma unroll
    for (int ks = 0; ks < 4; ++ks) {                 // 4 K-steps of 32 hw
      bf16x8 af[2], bfr[2];
      #pragma unroll
      for (int mm = 0; mm < 2; ++mm) {
        int row = (wm*2 + mm)*16 + l16;
        af[mm] = *(const bf16x8*)&kt[row*128 + (((ks*4 + lg) ^ (row & 15))*8)];
      }
      #pragma unroll
      for (int nn = 0; nn < 2; ++nn) {
        int row = (wn*2 + nn)*16 + l16;
        bfr[nn] = *(const bf16x8*)&qt[row*128 + (((ks*4 + lg) ^ (row & 15))*8)];
      }
      #pragma unroll
      for (int mm = 0; mm < 2; ++mm)
        #pragma unroll
        for (int nn = 0; nn < 2; ++nn)
          acc[mm][nn] = __builtin_amdgcn_mfma_f32_16x16x32_bf16(af[mm], bfr[nn], acc[mm][nn], 0, 0, 0);
    }
    __syncthreads();
  }
  float* gb = gp + ((size_t)slice*(B_*NH_) + bc) * 4096;
  #pragma unroll
  for (int mm = 0; mm < 2; ++mm) {
    #pragma unroll
    for (int nn = 0; nn < 2; ++nn) {
      int jj = (wn*2 + nn)*16 + l16;
      #pragma unroll
      for (int r = 0; r < 4; ++r) {
        int ii = (wm*2 + mm)*16 + lg*4 + r;
        if (ii < E_ && jj < E_) gb[ii*64 + jj] = acc[mm][nn][r];
      }
    }
  }
}

// ---------------- K3b: sum 4 slices, scale, softmax over i (per b,c,j) ----------------
__global__ __launch_bounds__(64) void k_softmax(const float* __restrict__ gp, float* __restrict__ wts) {
  int bc = blockIdx.x;
  int j = threadIdx.x;
  if (j >= E_) return;
  float lgt[E_];
  #pragma unroll
  for (int i = 0; i < E_; ++i) {
    float s = 0.f;
    #pragma unroll
    for (int sl = 0; sl < 4; ++sl) s += gp[((size_t)sl*(B_*NH_) + bc)*4096 + i*64 + j];
    lgt[i] = s * SCALE_;
  }
  float m = -1e30f;
  #pragma unroll
  for (int i = 0; i < E_; ++i) m = fmaxf(m, lgt[i]);
  float den = 0.f;
  #pragma unroll
  for (int i = 0; i < E_; ++i) { lgt[i] = expf(lgt[i] - m); den += lgt[i]; }
  float inv = 1.f / den;
  float* wb = wts + (size_t)bc * EE_;
  #pragma unroll
  for (int i = 0; i < E_; ++i) wb[i*E_ + j] = lgt[i] * inv;
}

// ---------------- K4: ensemble mixing via single MFMA GEMM ----------------
// T = W'^T V with W'[i][j] = w[i][j] + (i==j) - 1/E  (folds identity + mean-centering; sum_i w = 1)
__global__ __launch_bounds__(256) void k_mix(const bf16* __restrict__ vin, const float* __restrict__ wts,
                                             bf16* __restrict__ tout) {
  __shared__ short wl[64*64];      // 8 KB: A[j][i] = W'[i][j], 128B rows, chunk ^= (row&7)
  __shared__ short vt[64*VSTR];    // 16.5 KB: V tile [i][p], K-pad rows zeroed
  int bc = blockIdx.x;
  int b = bc >> 6, c = bc & 63;
  int p0 = blockIdx.y * 128;
  int tid = threadIdx.x;
  const float* wb = wts + (size_t)bc * EE_;
  for (int idx = tid; idx < 512; idx += 256) {       // 64 rows x 8 chunks
    int jr = idx >> 3, ch = idx & 7;
    bf16x8 vv;
    #pragma unroll
    for (int e = 0; e < 8; ++e) {
      int i = ch*8 + e;
      float v = 0.f;
      if (i < E_ && jr < E_) v = wb[i*E_ + jr] + ((i == jr) ? 1.f : 0.f) - (1.f/E_);
      vv[e] = f2b(v);
    }
    *(bf16x8*)&wl[jr*64 + ((ch ^ (jr & 7))*8)] = vv;
  }
  size_t vbase = (size_t)b * E_ * CHW_ + (size_t)c * HW_ + p0;
  for (int idx = tid; idx < 1024; idx += 256) {      // 64 rows x 16 chunks, zero pad rows (K-dim!)
    int i = idx >> 4, seg = idx & 15;
    uint4 v4 = {0u, 0u, 0u, 0u};
    if (i < E_) v4 = *(const uint4*)&vin[vbase + (size_t)i*CHW_ + seg*8];
    *(uint2*)&vt[i*VSTR + seg*8]     = make_uint2(v4.x, v4.y);
    *(uint2*)&vt[i*VSTR + seg*8 + 4] = make_uint2(v4.z, v4.w);
  }
  __syncthreads();
  int w = tid >> 6, lane = tid & 63, lg = lane >> 4, l16 = lane & 15;
  const f32x4 vzero = {0.f, 0.f, 0.f, 0.f};
  f32x4 acc[4][2];
  #pragma unroll
  for (int mf = 0; mf < 4; ++mf) { acc[mf][0] = vzero; acc[mf][1] = vzero; }
  #pragma unroll
  for (int kf = 0; kf < 2; ++kf) {
    bf16x8 bfr[2];
    #pragma unroll
    for (int cf = 0; cf < 2; ++cf)
      #pragma unroll
      for (int e = 0; e < 8; ++e)
        bfr[cf][e] = vt[(kf*32 + lg*8 + e)*VSTR + w*32 + cf*16 + l16];
    #pragma unroll
    for (int mf = 0; mf < 4; ++mf) {
      int row = mf*16 + l16;
      bf16x8 afr = *(const bf16x8*)&wl[row*64 + (((kf*4 + lg) ^ (row & 7))*8)];
      #pragma unroll
      for (int cf = 0; cf < 2; ++cf)
        acc[mf][cf] = __builtin_amdgcn_mfma_f32_16x16x32_bf16(afr, bfr[cf], acc[mf][cf], 0, 0, 0);
    }
  }
  #pragma unroll
  for (int mf = 0; mf < 4; ++mf) {
    #pragma unroll
    for (int cf = 0; cf < 2; ++cf) {
      int pp = p0 + w*32 + cf*16 + l16;
      #pragma unroll
      for (int r = 0; r < 4; ++r) {
        int jj = mf*16 + lg*4 + r;
        if (jj < E_)
          tout[(size_t)b*E_*CHW_ + (size_t)jj*CHW_ + (size_t)c*HW_ + pp] = __float2bfloat16(acc[mf][cf][r]);
      }
    }
  }
}

// ---------------- K5: after = x + Wo*t ; out = after + MLP(after) via 3 chained MFMA GEMMs ----------------
__global__ __launch_bounds__(256) void k_final(const bf16* __restrict__ tin, const float* __restrict__ x,
                                               const float* __restrict__ Wo, const float* __restrict__ Wm1,
                                               const float* __restrict__ bm1, const float* __restrict__ Wm2,
                                               const float* __restrict__ bm2, float* __restrict__ out) {
  __shared__ short wl[192*WSTR];
  __shared__ short tl[64*PSTR];
  __shared__ short al[64*PSTR];
  int be = blockIdx.x, p0 = blockIdx.y * 128;
  int tid = threadIdx.x;
  for (int idx = tid; idx < 6144; idx += 256) {
    int n = idx >> 5, cp = idx & 31;
    const float* Wsrc = (n < 64) ? Wo : (n < 128 ? Wm1 : Wm2);
    float2 wv = *(const float2*)&Wsrc[(n & 63)*64 + cp*2];
    *(unsigned*)&wl[n*WSTR + cp*2] = pack2(wv.x, wv.y);
  }
  for (int idx = tid; idx < 4096; idx += 256) {
    int o = idx >> 6, seg = idx & 63;
    *(unsigned*)&tl[o*PSTR + seg*2] =
        *(const unsigned*)&tin[(size_t)be*CHW_ + (size_t)o*HW_ + p0 + seg*2];
  }
  __syncthreads();
  int wave = tid >> 6, lane = tid & 63, lg = lane >> 4, l16 = lane & 15;
  int colb0 = wave*32;
  const f32x4 vzero = {0.f, 0.f, 0.f, 0.f};

  f32x4 aft[4][2];
  #pragma unroll
  for (int mf = 0; mf < 4; ++mf) { aft[mf][0] = vzero; aft[mf][1] = vzero; }
  #pragma unroll
  for (int cf = 0; cf < 2; ++cf) {
    int colb = colb0 + cf*16;
    #pragma unroll
    for (int kf = 0; kf < 2; ++kf) {
      bf16x8 bfr;
      #pragma unroll
      for (int e = 0; e < 8; ++e) bfr[e] = tl[(kf*32 + lg*8 + e)*PSTR + colb + l16];
      #pragma unroll
      for (int mf = 0; mf < 4; ++mf) {
        bf16x8 afr = *(const bf16x8*)&wl[(mf*16 + l16)*WSTR + kf*32 + lg*8];
        aft[mf][cf] = __builtin_amdgcn_mfma_f32_16x16x32_bf16(afr, bfr, aft[mf][cf], 0, 0, 0);
      }
    }
  }
  #pragma unroll
  for (int mf = 0; mf < 4; ++mf) {
    int c0 = mf*16 + lg*4;
    #pragma unroll
    for (int cf = 0; cf < 2; ++cf) {
      int pp = p0 + colb0 + cf*16 + l16;
      #pragma unroll
      for (int r = 0; r < 4; ++r) {
        float v = aft[mf][cf][r] + x[(size_t)be*CHW_ + (size_t)(c0+r)*HW_ + pp];
        aft[mf][cf][r] = v;
        al[(c0+r)*PSTR + colb0 + cf*16 + l16] = f2b(v);
      }
    }
  }
  __syncthreads();
  f32x4 hh[4][2];
  #pragma unroll
  for (int mf = 0; mf < 4; ++mf) { hh[mf][0] = vzero; hh[mf][1] = vzero; }
  #pragma unroll
  for (int cf = 0; cf < 2; ++cf) {
    int colb = colb0 + cf*16;
    #pragma unroll
    for (int kf = 0; kf < 2; ++kf) {
      bf16x8 bfr;
      #pragma unroll
      for (int e = 0; e < 8; ++e) bfr[e] = al[(kf*32 + lg*8 + e)*PSTR + colb + l16];
      #pragma unroll
      for (int mf = 0; mf < 4; ++mf) {
        bf16x8 afr = *(const bf16x8*)&wl[((64 + mf*16 + l16))*WSTR + kf*32 + lg*8];
        hh[mf][cf] = __builtin_amdgcn_mfma_f32_16x16x32_bf16(afr, bfr, hh[mf][cf], 0, 0, 0);
      }
    }
  }
  __syncthreads();
  #pragma unroll
  for (int mf = 0; mf < 4; ++mf) {
    int m0 = mf*16 + lg*4;
    #pragma unroll
    for (int cf = 0; cf < 2; ++cf) {
      #pragma unroll
      for (int r = 0; r < 4; ++r) {
        float hv = hh[mf][cf][r] + bm1[m0 + r];
        float g = 0.5f * hv * (1.f + erff(hv * 0.70710678118654752440f));
        al[(m0+r)*PSTR + colb0 + cf*16 + l16] = f2b(g);
      }
    }
  }
  __syncthreads();
  f32x4 mx[4][2];
  #pragma unroll
  for (int mf = 0; mf < 4; ++mf) { mx[mf][0] = vzero; mx[mf][1] = vzero; }
  #pragma unroll
  for (int cf = 0; cf < 2; ++cf) {
    int colb = colb0 + cf*16;
    #pragma unroll
    for (int kf = 0; kf < 2; ++kf) {
      bf16x8 bfr;
      #pragma unroll
      for (int e = 0; e < 8; ++e) bfr[e] = al[(kf*32 + lg*8 + e)*PSTR + colb + l16];
      #pragma unroll
      for (int mf = 0; mf < 4; ++mf) {
        bf16x8 afr = *(const bf16x8*)&wl[((128 + mf*16 + l16))*WSTR + kf*32 + lg*8];
        mx[mf][cf] = __builtin_amdgcn_mfma_f32_16x16x32_bf16(afr, bfr, mx[mf][cf], 0, 0, 0);
      }
    }
  }
  #pragma unroll
  for (int mf = 0; mf < 4; ++mf) {
    int c0 = mf*16 + lg*4;
    #pragma unroll
    for (int cf = 0; cf < 2; ++cf) {
      int pp = p0 + colb0 + cf*16 + l16;
      #pragma unroll
      for (int r = 0; r < 4; ++r)
        out[(size_t)be*CHW_ + (size_t)(c0+r)*HW_ + pp] = aft[mf][cf][r] + mx[mf][cf][r] + bm2[c0+r];
    }
  }
}

extern "C" void kernel_launch(void* const* d_in, const int* in_sizes, int n_in,
                              void* d_out, int out_size, void* d_ws, size_t ws_size,
                              hipStream_t stream) {
  (void)in_sizes; (void)n_in; (void)out_size; (void)ws_size;
  const float* x   = (const float*)d_in[0];
  const float* lng = (const float*)d_in[1];
  const float* lnb = (const float*)d_in[2];
  const float* Wv  = (const float*)d_in[3];
  const float* Wk  = (const float*)d_in[4];
  const float* Wq  = (const float*)d_in[5];
  const float* Wo  = (const float*)d_in[6];
  const float* Wm1 = (const float*)d_in[7];
  const float* bm1 = (const float*)d_in[8];
  const float* Wm2 = (const float*)d_in[9];
  const float* bm2 = (const float*)d_in[10];
  float* out = (float*)d_out;

  char* ws = (char*)d_ws;
  size_t off = 0;
  float* sums  = (float*)(ws + off); off += 2048;
  float* stats = (float*)(ws + off); off += 2048;
  float* wts   = (float*)(ws + off); off += (size_t)B_*NH_*EE_*4;       // 2.56 MB
  float* gramp = (float*)(ws + off); off += (size_t)4*B_*NH_*4096*4;    // 16.8 MB (4 K-slices, 64x64)
  bf16* vbuf   = (bf16*)(ws + off);  off += (size_t)BE_*CHW_*2;         // 52.4 MB
  bf16* kbuf   = (bf16*)(ws + off);  off += (size_t)BE_*CHW_*2;
  bf16* qbuf   = (bf16*)(ws + off);  off += (size_t)BE_*CHW_*2;
  bf16* tbuf   = kbuf;  // k dead after k_gram; reuse for transformed

  hipMemsetAsync(sums, 0, 2048, stream);
  k_stats_p<<<dim3(BE_*4), 256, 0, stream>>>(x, sums);
  k_stats_f<<<dim3(1), 256, 0, stream>>>(sums, stats);
  k_vkq<<<dim3(BE_, 16), 256, 0, stream>>>(x, lng, lnb, Wv, Wk, Wq, stats, vbuf, kbuf, qbuf);
  k_gram<<<dim3(B_*NH_, 4), 256, 0, stream>>>(kbuf, qbuf, gramp);
  k_softmax<<<dim3(B_*NH_), 64, 0, stream>>>(gramp, wts);
  k_mix<<<dim3(B_*NH_, 16), 256, 0, stream>>>(vbuf, wts, tbuf);
  k_final<<<dim3(BE_, 16), 256, 0, stream>>>(tbuf, x, Wo, Wm1, bm1, Wm2, bm2, out);
}